// Round 1
// baseline (678.668 us; speedup 1.0000x reference)
//
#include <hip/hip_runtime.h>
#include <stdint.h>

// Problem constants (fixed by setup_inputs)
#define CCH 64
#define HW  (1024 * 1024)   // H*W, also 2^20
#define NPIX (1024 * 1024)
#define NSEG 4096
#define NBIN 65536          // pos >> 4 buckets (one 64B line of a plane per bucket)

// ws layout (bytes):
// 0                  packed  u32[NPIX]      4 MB   (seg<<20 | pos)
// 4 MB               sorted  u32[NPIX]      4 MB
// 8 MB               hist    u32[NBIN]      256 KB
// 8 MB + 256 KB      cursor  u32[NBIN]      256 KB
// 8 MB + 512 KB      segcnt  u32[NSEG*16]   256 KB  (padded x16 to spread atomic lines)

__global__ void k1_pack_hist(const int* __restrict__ pix_yx,
                             const int* __restrict__ seg,
                             uint32_t* __restrict__ packed,
                             uint32_t* __restrict__ hist,
                             uint32_t* __restrict__ segcnt) {
    int n = blockIdx.x * blockDim.x + threadIdx.x;
    int2 yx = ((const int2*)pix_yx)[n];          // .x = y, .y = x
    uint32_t s = (uint32_t)seg[n];
    uint32_t pos = ((uint32_t)yx.x << 10) | (uint32_t)yx.y;
    packed[n] = (s << 20) | pos;
    atomicAdd(&hist[pos >> 4], 1u);
    atomicAdd(&segcnt[s * 16], 1u);
}

// Single block, 1024 threads; each thread owns 64 consecutive bins.
__global__ void k2_scan(const uint32_t* __restrict__ hist,
                        uint32_t* __restrict__ cursor) {
    __shared__ uint32_t sh[1024];
    int tid = threadIdx.x;
    uint32_t local[64];
    uint32_t tot = 0;
#pragma unroll
    for (int j = 0; j < 64; ++j) { local[j] = hist[tid * 64 + j]; tot += local[j]; }
    sh[tid] = tot;
    __syncthreads();
    // Hillis-Steele inclusive scan over 1024 thread-totals
    for (int off = 1; off < 1024; off <<= 1) {
        uint32_t v = (tid >= off) ? sh[tid - off] : 0u;
        __syncthreads();
        sh[tid] += v;
        __syncthreads();
    }
    uint32_t run = sh[tid] - tot;  // exclusive base for this thread's bins
#pragma unroll
    for (int j = 0; j < 64; ++j) { cursor[tid * 64 + j] = run; run += local[j]; }
}

__global__ void k3_scatter(const uint32_t* __restrict__ packed,
                           uint32_t* __restrict__ cursor,
                           uint32_t* __restrict__ sorted) {
    int n = blockIdx.x * blockDim.x + threadIdx.x;
    uint32_t p = packed[n];
    uint32_t d = atomicAdd(&cursor[(p & 0xFFFFFu) >> 4], 1u);
    sorted[d] = p;
}

// Main kernel: 1024 entries per block. LDS transpose tile so that
//   loads  : lane = pixel (sorted positions -> near-coalesced)
//   atomics: lane = channel (64 consecutive floats -> 2 cache lines)
__global__ __launch_bounds__(256) void k4_stream(const float* __restrict__ feat,
                                                 const uint32_t* __restrict__ sorted,
                                                 float* __restrict__ sums) {
    __shared__ float tile[64 * 65];      // [pixel][channel], +1 pad
    __shared__ uint32_t epack[1024];
    const int tid = threadIdx.x;
    const int w = tid >> 6;              // wave id 0..3
    const int l = tid & 63;              // lane
    const int base = blockIdx.x * 1024;

    for (int i = tid; i < 1024; i += 256) epack[i] = sorted[base + i];
    __syncthreads();

    for (int t = 0; t < 16; ++t) {
        // load phase: lane l = pixel t*64+l, wave w covers channels [16w,16w+16)
        uint32_t pk = epack[t * 64 + l];
        const float* fp = feat + (pk & 0xFFFFFu);
#pragma unroll
        for (int cc = 0; cc < 16; ++cc) {
            int c = (w << 4) + cc;
            tile[l * 65 + c] = fp[(size_t)c * HW];
        }
        __syncthreads();
        // atomic phase: lane l = channel, wave w covers pixels [16w,16w+16)
#pragma unroll
        for (int pp = 0; pp < 16; ++pp) {
            int p = (w << 4) + pp;
            uint32_t sg = epack[t * 64 + p] >> 20;    // broadcast read
            atomicAdd(&sums[sg * 64 + l], tile[p * 65 + l]);
        }
        __syncthreads();
    }
}

__global__ void k5_div(float* __restrict__ out,
                       const uint32_t* __restrict__ segcnt) {
    int i = blockIdx.x * blockDim.x + threadIdx.x;   // 0 .. 262143
    uint32_t cnt = segcnt[(i >> 6) * 16];
    float c = (float)(cnt ? cnt : 1u);
    out[i] = out[i] / c;
}

extern "C" void kernel_launch(void* const* d_in, const int* in_sizes, int n_in,
                              void* d_out, int out_size, void* d_ws, size_t ws_size,
                              hipStream_t stream) {
    const float* feat = (const float*)d_in[0];
    const int*   pix  = (const int*)d_in[1];
    const int*   seg  = (const int*)d_in[2];
    float* out = (float*)d_out;

    uint8_t* ws = (uint8_t*)d_ws;
    uint32_t* packed = (uint32_t*)(ws);
    uint32_t* sorted = (uint32_t*)(ws + (4u << 20));
    uint32_t* hist   = (uint32_t*)(ws + (8u << 20));
    uint32_t* cursor = (uint32_t*)(ws + (8u << 20) + (256u << 10));
    uint32_t* segcnt = (uint32_t*)(ws + (8u << 20) + (512u << 10));

    hipMemsetAsync(out, 0, (size_t)NSEG * CCH * sizeof(float), stream);
    hipMemsetAsync(hist, 0, (size_t)NBIN * sizeof(uint32_t), stream);
    hipMemsetAsync(segcnt, 0, (size_t)NSEG * 16 * sizeof(uint32_t), stream);

    k1_pack_hist<<<NPIX / 256, 256, 0, stream>>>(pix, seg, packed, hist, segcnt);
    k2_scan<<<1, 1024, 0, stream>>>(hist, cursor);
    k3_scatter<<<NPIX / 256, 256, 0, stream>>>(packed, cursor, sorted);
    k4_stream<<<NPIX / 1024, 256, 0, stream>>>(feat, sorted, out);
    k5_div<<<(NSEG * CCH) / 256, 256, 0, stream>>>(out, segcnt);
}

// Round 2
// 650.211 us; speedup vs baseline: 1.0438x; 1.0438x over previous
//
#include <hip/hip_runtime.h>
#include <stdint.h>

// Problem constants (fixed by setup_inputs)
#define CCH 64
#define HW  (1024 * 1024)
#define NPIX (1024 * 1024)
#define NSEG 4096
#define NBIN 65536          // pos >> 4 buckets

// ws layout (KB offsets):
//      0  packed        u32[NPIX]        4096 KB
//   4096  sortedPos     u32[NPIX]        4096 KB
//   8192  poshist       u32[NBIN]         256 KB
//   8448  posLocal      u32[NBIN]         256 KB  (local exclusive scan)
//   8704  posBlk        u32[64]             4 KB
//   8708  posBlkExc     u32[64]             4 KB
//   8712  segOff        u32[NSEG]          16 KB
//   8736  seghistPad    u32[NSEG*16]      256 KB  (counts, 1 bin / 64B line)
//   8992  segCursorPad  u32[NSEG*16]      256 KB
//  10240  posCursorPad  u32[NBIN*16]     4096 KB  (1 bin / 64B line)
//  16384  gathered      u32[NPIX*32]   131072 KB  (bf16-pair packed, 128 MB)
#define WS_NEED ((size_t)147456 * 1024)

__device__ inline uint32_t pack_bf16(float a, float b) {
    uint32_t ua = __float_as_uint(a), ub = __float_as_uint(b);
    ua = (ua + 0x7FFFu + ((ua >> 16) & 1u)) >> 16;   // RNE
    ub = (ub + 0x7FFFu + ((ub >> 16) & 1u)) >> 16;
    return (ub << 16) | ua;                           // lo = a (ch 2k), hi = b (ch 2k+1)
}
__device__ inline float bf_lo(uint32_t v) { return __uint_as_float(v << 16); }
__device__ inline float bf_hi(uint32_t v) { return __uint_as_float(v & 0xFFFF0000u); }

__global__ void k1_pack_hist(const int* __restrict__ pix_yx,
                             const int* __restrict__ seg,
                             uint32_t* __restrict__ packed,
                             uint32_t* __restrict__ poshist,
                             uint32_t* __restrict__ seghistPad) {
    int n = blockIdx.x * blockDim.x + threadIdx.x;
    int2 yx = ((const int2*)pix_yx)[n];
    uint32_t s = (uint32_t)seg[n];
    uint32_t pos = ((uint32_t)yx.x << 10) | (uint32_t)yx.y;
    packed[n] = (s << 20) | pos;
    atomicAdd(&poshist[pos >> 4], 1u);
    atomicAdd(&seghistPad[s * 16], 1u);
}

// 64 blocks x 1024: local inclusive scan of poshist; write local EXCLUSIVE + block total
__global__ void k2a_scan_local(const uint32_t* __restrict__ poshist,
                               uint32_t* __restrict__ posLocal,
                               uint32_t* __restrict__ posBlk) {
    __shared__ uint32_t sh[1024];
    int t = threadIdx.x, b = blockIdx.x;
    int i = b * 1024 + t;
    uint32_t v = poshist[i];
    sh[t] = v;
    __syncthreads();
    for (int off = 1; off < 1024; off <<= 1) {
        uint32_t u = (t >= off) ? sh[t - off] : 0u;
        __syncthreads();
        sh[t] += u;
        __syncthreads();
    }
    uint32_t inc = sh[t];
    posLocal[i] = inc - v;
    if (t == 1023) posBlk[b] = inc;
}

// 1 block x 1024: scan 64 block totals (wave 0) + scan seghist (all threads, 4 bins each)
__global__ void k2b_scan_tops(const uint32_t* __restrict__ posBlk,
                              uint32_t* __restrict__ posBlkExc,
                              const uint32_t* __restrict__ seghistPad,
                              uint32_t* __restrict__ segOff,
                              uint32_t* __restrict__ segCursorPad) {
    int t = threadIdx.x;
    if (t < 64) {                       // single wave: shuffle inclusive scan
        uint32_t v = posBlk[t];
        uint32_t x = v;
        for (int off = 1; off < 64; off <<= 1) {
            uint32_t u = __shfl_up(x, off);
            if ((t & 63) >= off) x += u;
        }
        posBlkExc[t] = x - v;
    }
    // segment scan: thread t owns bins 4t..4t+3
    uint32_t c0 = seghistPad[(4 * t + 0) * 16];
    uint32_t c1 = seghistPad[(4 * t + 1) * 16];
    uint32_t c2 = seghistPad[(4 * t + 2) * 16];
    uint32_t c3 = seghistPad[(4 * t + 3) * 16];
    uint32_t tot = c0 + c1 + c2 + c3;
    __shared__ uint32_t sh[1024];
    sh[t] = tot;
    __syncthreads();
    for (int off = 1; off < 1024; off <<= 1) {
        uint32_t u = (t >= off) ? sh[t - off] : 0u;
        __syncthreads();
        sh[t] += u;
        __syncthreads();
    }
    uint32_t base = sh[t] - tot;
    uint32_t o0 = base, o1 = base + c0, o2 = o1 + c1, o3 = o2 + c2;
    ((uint4*)segOff)[t] = make_uint4(o0, o1, o2, o3);
    segCursorPad[(4 * t + 0) * 16] = o0;
    segCursorPad[(4 * t + 1) * 16] = o1;
    segCursorPad[(4 * t + 2) * 16] = o2;
    segCursorPad[(4 * t + 3) * 16] = o3;
}

// 64 blocks x 1024: final cursor = local exclusive + block offset, padded 1-per-line
__global__ void k2c_scan_add(const uint32_t* __restrict__ posLocal,
                             const uint32_t* __restrict__ posBlkExc,
                             uint32_t* __restrict__ posCursorPad) {
    int t = threadIdx.x, b = blockIdx.x;
    int i = b * 1024 + t;
    posCursorPad[(size_t)i * 16] = posLocal[i] + posBlkExc[b];
}

__global__ void k3_scatter(const uint32_t* __restrict__ packed,
                           uint32_t* __restrict__ posCursorPad,
                           uint32_t* __restrict__ sorted) {
    int n = blockIdx.x * blockDim.x + threadIdx.x;
    uint32_t p = packed[n];
    uint32_t d = atomicAdd(&posCursorPad[(size_t)((p & 0xFFFFFu) >> 4) * 16], 1u);
    sorted[d] = p;
}

// Main gather: position-sorted loads, bf16-packed transposed write to segment-rank rows.
// 1 atomic per PIXEL (rank), zero output atomics.
__global__ __launch_bounds__(256) void k4_gather(const float* __restrict__ feat,
                                                 const uint32_t* __restrict__ sorted,
                                                 uint32_t* __restrict__ segCursorPad,
                                                 uint32_t* __restrict__ gathered) {
    __shared__ uint32_t epack[1024];
    __shared__ uint32_t rnk[1024];
    __shared__ uint32_t tile_pk[64 * 33];   // [pixel][chan-pair], +1 pad
    const int tid = threadIdx.x;
    const int w = tid >> 6;                 // wave 0..3
    const int l = tid & 63;
    const int base = blockIdx.x * 1024;

#pragma unroll
    for (int i = 0; i < 4; ++i) epack[tid + 256 * i] = sorted[base + tid + 256 * i];
    __syncthreads();
#pragma unroll
    for (int i = 0; i < 4; ++i) {
        int idx = tid * 4 + i;
        uint32_t sg = epack[idx] >> 20;
        rnk[idx] = atomicAdd(&segCursorPad[sg * 16], 1u);
    }
    __syncthreads();

    for (int t = 0; t < 16; ++t) {
        // load phase: lane = pixel (sorted pos), wave w covers chan-pairs [8w, 8w+8)
        uint32_t pk = epack[t * 64 + l];
        const float* fp = feat + (pk & 0xFFFFFu);
#pragma unroll
        for (int kk = 0; kk < 8; ++kk) {
            int k = w * 8 + kk;
            float a = fp[(size_t)(2 * k) * HW];
            float b = fp[(size_t)(2 * k + 1) * HW];
            tile_pk[l * 33 + k] = pack_bf16(a, b);
        }
        __syncthreads();
        // write phase: half-wave = pixel, lane&31 = chan-pair -> 128B contiguous rows
#pragma unroll
        for (int pp = 0; pp < 16; pp += 2) {
            int p = w * 16 + pp + (l >> 5);
            int k = l & 31;
            uint32_t r = rnk[t * 64 + p];
            gathered[(size_t)r * 32 + k] = tile_pk[p * 33 + k];
        }
        __syncthreads();
    }
}

// One block per segment: stream its contiguous rows, reduce, divide, store.
__global__ __launch_bounds__(256) void k5_reduce(const uint32_t* __restrict__ gathered,
                                                 const uint32_t* __restrict__ segOff,
                                                 const uint32_t* __restrict__ seghistPad,
                                                 float* __restrict__ out) {
    const int s = blockIdx.x;
    const int tid = threadIdx.x;
    const int k = tid & 31;        // chan-pair
    const int sub = tid >> 5;      // 0..7 row-group
    uint32_t base = segOff[s];
    uint32_t cnt = seghistPad[s * 16];
    float a0 = 0.f, a1 = 0.f;
    for (uint32_t r = sub; r < cnt; r += 8) {
        uint32_t v = gathered[(size_t)(base + r) * 32 + k];
        a0 += bf_lo(v);
        a1 += bf_hi(v);
    }
    __shared__ float red0[8][32];
    __shared__ float red1[8][32];
    red0[sub][k] = a0;
    red1[sub][k] = a1;
    __syncthreads();
    if (tid < 32) {
        float s0 = 0.f, s1 = 0.f;
#pragma unroll
        for (int j = 0; j < 8; ++j) { s0 += red0[j][tid]; s1 += red1[j][tid]; }
        float inv = 1.0f / (float)(cnt ? cnt : 1u);
        ((float2*)out)[s * 32 + tid] = make_float2(s0 * inv, s1 * inv);
    }
}

// ---------- fallback path (small ws): R1's atomic kernel ----------
__global__ __launch_bounds__(256) void k4_stream(const float* __restrict__ feat,
                                                 const uint32_t* __restrict__ sorted,
                                                 float* __restrict__ sums) {
    __shared__ float tile[64 * 65];
    __shared__ uint32_t epack[1024];
    const int tid = threadIdx.x;
    const int w = tid >> 6;
    const int l = tid & 63;
    const int base = blockIdx.x * 1024;
    for (int i = tid; i < 1024; i += 256) epack[i] = sorted[base + i];
    __syncthreads();
    for (int t = 0; t < 16; ++t) {
        uint32_t pk = epack[t * 64 + l];
        const float* fp = feat + (pk & 0xFFFFFu);
#pragma unroll
        for (int cc = 0; cc < 16; ++cc) {
            int c = (w << 4) + cc;
            tile[l * 65 + c] = fp[(size_t)c * HW];
        }
        __syncthreads();
#pragma unroll
        for (int pp = 0; pp < 16; ++pp) {
            int p = (w << 4) + pp;
            uint32_t sg = epack[t * 64 + p] >> 20;
            atomicAdd(&sums[sg * 64 + l], tile[p * 65 + l]);
        }
        __syncthreads();
    }
}

__global__ void k5_div(float* __restrict__ out, const uint32_t* __restrict__ seghistPad) {
    int i = blockIdx.x * blockDim.x + threadIdx.x;
    uint32_t cnt = seghistPad[(i >> 6) * 16];
    float c = (float)(cnt ? cnt : 1u);
    out[i] = out[i] / c;
}

extern "C" void kernel_launch(void* const* d_in, const int* in_sizes, int n_in,
                              void* d_out, int out_size, void* d_ws, size_t ws_size,
                              hipStream_t stream) {
    const float* feat = (const float*)d_in[0];
    const int*   pix  = (const int*)d_in[1];
    const int*   seg  = (const int*)d_in[2];
    float* out = (float*)d_out;

    uint8_t* ws = (uint8_t*)d_ws;
    uint32_t* packed       = (uint32_t*)(ws);
    uint32_t* sortedPos    = (uint32_t*)(ws + (size_t)4096 * 1024);
    uint32_t* poshist      = (uint32_t*)(ws + (size_t)8192 * 1024);
    uint32_t* posLocal     = (uint32_t*)(ws + (size_t)8448 * 1024);
    uint32_t* posBlk       = (uint32_t*)(ws + (size_t)8704 * 1024);
    uint32_t* posBlkExc    = (uint32_t*)(ws + (size_t)8708 * 1024);
    uint32_t* segOff       = (uint32_t*)(ws + (size_t)8712 * 1024);
    uint32_t* seghistPad   = (uint32_t*)(ws + (size_t)8736 * 1024);
    uint32_t* segCursorPad = (uint32_t*)(ws + (size_t)8992 * 1024);
    uint32_t* posCursorPad = (uint32_t*)(ws + (size_t)10240 * 1024);
    uint32_t* gathered     = (uint32_t*)(ws + (size_t)16384 * 1024);

    hipMemsetAsync(poshist, 0, (size_t)NBIN * sizeof(uint32_t), stream);
    hipMemsetAsync(seghistPad, 0, (size_t)NSEG * 16 * sizeof(uint32_t), stream);
    hipMemsetAsync(out, 0, (size_t)NSEG * CCH * sizeof(float), stream);

    k1_pack_hist<<<NPIX / 256, 256, 0, stream>>>(pix, seg, packed, poshist, seghistPad);
    k2a_scan_local<<<64, 1024, 0, stream>>>(poshist, posLocal, posBlk);
    k2b_scan_tops<<<1, 1024, 0, stream>>>(posBlk, posBlkExc, seghistPad, segOff, segCursorPad);
    k2c_scan_add<<<64, 1024, 0, stream>>>(posLocal, posBlkExc, posCursorPad);
    k3_scatter<<<NPIX / 256, 256, 0, stream>>>(packed, posCursorPad, sortedPos);

    if (ws_size >= WS_NEED) {
        k4_gather<<<NPIX / 1024, 256, 0, stream>>>(feat, sortedPos, segCursorPad, gathered);
        k5_reduce<<<NSEG, 256, 0, stream>>>(gathered, segOff, seghistPad, out);
    } else {
        k4_stream<<<NPIX / 1024, 256, 0, stream>>>(feat, sortedPos, out);
        k5_div<<<(NSEG * CCH) / 256, 256, 0, stream>>>(out, seghistPad);
    }
}